// Round 1
// baseline (143.015 us; speedup 1.0000x reference)
//
#include <hip/hip_runtime.h>

typedef __attribute__((ext_vector_type(8))) short short8;
typedef __attribute__((ext_vector_type(4))) float f32x4;
typedef unsigned short u16;

__device__ __forceinline__ u16 f2bf(float f) {
    unsigned u = __builtin_bit_cast(unsigned, f);
    unsigned r = u + 0x7fffu + ((u >> 16) & 1u);
    return (u16)(r >> 16);
}

// ---------------- K0: prep (zero out, pack weights, pose const) --------------
__global__ __launch_bounds__(256) void k0_prep(
    const float* __restrict__ z, const float* __restrict__ w1,
    const float* __restrict__ w2, const float* __restrict__ wfc1,
    const float* __restrict__ wpose, const float* __restrict__ bpose,
    const float* __restrict__ wfc2, const float* __restrict__ bfc2,
    float* __restrict__ out, u16* __restrict__ w1p, u16* __restrict__ w2p,
    u16* __restrict__ fc1T, float* __restrict__ cst)
{
    int gt = blockIdx.x * 256 + threadIdx.x;   // 0..16383
    out[gt] = 0.f;                             // zero heat (borders stay 0)

    if (gt < 1536) {                           // w1 pack: [3 ksteps][64 lanes][8]
        int l = (gt >> 3) & 63, j = gt & 7, s = gt >> 9;
        int k = s * 32 + ((l >> 4) << 3) + j;
        int o = l & 15;
        w1p[gt] = (k < 81) ? f2bf(w1[o * 81 + k]) : (u16)0;
    }
    if (gt < 6656) {                           // w2 pack: [13][64][8], k = tap*16+ci
        int l = (gt >> 3) & 63, j = gt & 7, s = gt >> 9;
        int k = s * 32 + ((l >> 4) << 3) + j;
        int o = l & 15;
        int tap = k >> 4, ci = k & 15;
        w2p[gt] = (tap < 25) ? f2bf(w2[o * 400 + ci * 25 + tap]) : (u16)0;
    }
    {                                          // fc1 transpose-pack: [128 n][1024 k]
        int base = gt * 8;
        int n = base >> 10, kk = base & 1023;
        short8 v;
        #pragma unroll
        for (int j = 0; j < 8; ++j) v[j] = (short)f2bf(wfc1[(kk + j) * 128 + n]);
        *(short8*)&fc1T[base] = v;
    }
    if (gt == 0) {                             // pose branch + b_fc2 constant
        float zz = z[0];
        float s = bfc2[0];
        for (int j = 0; j < 16; ++j) {
            float p = fmaxf(zz * wpose[j] + bpose[j], 0.f);
            s += p * wfc2[128 + j];
        }
        *cst = s;
    }
}

// ---------------- K1: per-patch conv1+pool1+conv2+pool2 ----------------------
__global__ __launch_bounds__(256) void k1_feat(
    const float* __restrict__ x, const u16* __restrict__ w1p,
    const u16* __restrict__ w2p, const float* __restrict__ b1g,
    const float* __restrict__ b2g, u16* __restrict__ feat)
{
    __shared__ u16 s_in[44 * 40];        // padded patch (rows 36..43 extra pad)
    __shared__ u16 s_h1p[20 * 20 * 16];  // pool1 out, padded, channel-last
    __shared__ u16 s_feat[1024];

    const int tid = threadIdx.x;
    const int lane = tid & 63;
    const int wv = tid >> 6;
    const int mm = lane & 15;
    const int bq = lane >> 4;
    const int blk = blockIdx.x;
    const int py = blk / 96, px = blk % 96;

    {   // zero LDS (pads must be 0)
        uint4 z4 = {0, 0, 0, 0};
        uint4* p1 = (uint4*)s_in;
        for (int i = tid; i < 220; i += 256) p1[i] = z4;
        uint4* p2 = (uint4*)s_h1p;
        for (int i = tid; i < 800; i += 256) p2[i] = z4;
    }

    // weight fragments + biases (L2-hot)
    short8 w1f[3], w2f[13];
    #pragma unroll
    for (int s = 0; s < 3; ++s) w1f[s] = *(const short8*)&w1p[(s * 64 + lane) * 8];
    #pragma unroll
    for (int s = 0; s < 13; ++s) w2f[s] = *(const short8*)&w2p[(s * 64 + lane) * 8];
    const float bias1 = b1g[mm], bias2 = b2g[mm];

    // per-lane tap offset tables (static-indexed -> registers)
    int c1off[24];
    #pragma unroll
    for (int s = 0; s < 3; ++s)
        #pragma unroll
        for (int j = 0; j < 8; ++j) {
            int k = s * 32 + bq * 8 + j;
            int dy = k / 9, dx = k % 9;
            c1off[s * 8 + j] = dy * 40 + dx;   // k>=81 reads junk, weight is 0
        }
    int c2off[13];
    #pragma unroll
    for (int s = 0; s < 13; ++s) {
        int tap = s * 2 + (bq >> 1);
        if (tap > 24) tap = 0;                 // zero-weight pad tap
        int dy = tap / 5, dx = tap % 5;
        c2off[s] = (dy * 20 + dx) * 16 + (bq & 1) * 8;
    }
    __syncthreads();

    // load patch -> bf16 padded LDS
    for (int i = tid; i < 1024; i += 256) {
        int r = i >> 5, c = i & 31;
        s_in[(4 + r) * 40 + 4 + c] = f2bf(x[(py + r) * 128 + (px + c)]);
    }
    __syncthreads();

    // conv1 (M=16 cols of row pair, N=16 ch, K=96) + fused pool1
    for (int pi = 0; pi < 8; ++pi) {
        int q = wv + ((pi >> 1) << 2);         // 0..15 across waves
        int h = pi & 1;
        int base = (2 * q) * 40 + h * 16 + mm;
        f32x4 accA = {0, 0, 0, 0}, accB = {0, 0, 0, 0};
        #pragma unroll
        for (int s = 0; s < 3; ++s) {
            short8 aA, aB;
            #pragma unroll
            for (int j = 0; j < 8; ++j) {
                int o = base + c1off[s * 8 + j];
                aA[j] = (short)s_in[o];
                aB[j] = (short)s_in[o + 40];
            }
            accA = __builtin_amdgcn_mfma_f32_16x16x32_bf16(aA, w1f[s], accA, 0, 0, 0);
            accB = __builtin_amdgcn_mfma_f32_16x16x32_bf16(aB, w1f[s], accB, 0, 0, 0);
        }
        #pragma unroll
        for (int r = 0; r < 2; ++r) {          // 2x2 maxpool + bias + relu
            float v = fmaxf(fmaxf(accA[2 * r], accA[2 * r + 1]),
                            fmaxf(accB[2 * r], accB[2 * r + 1]));
            v = fmaxf(v + bias1, 0.f);
            int pc = h * 8 + (bq << 1) + r;
            s_h1p[((2 + q) * 20 + (2 + pc)) * 16 + mm] = f2bf(v);
        }
    }
    __syncthreads();

    // conv2 (M=16 cols of row pair, N=16 ch, K=416) + fused pool2
    for (int pi = 0; pi < 2; ++pi) {
        int q = wv + pi * 4;                   // 0..7
        int base = ((2 * q) * 20 + mm) * 16;
        f32x4 accA = {0, 0, 0, 0}, accB = {0, 0, 0, 0};
        #pragma unroll
        for (int s = 0; s < 13; ++s) {
            short8 aA = *(const short8*)&s_h1p[base + c2off[s]];
            short8 aB = *(const short8*)&s_h1p[base + 320 + c2off[s]];
            accA = __builtin_amdgcn_mfma_f32_16x16x32_bf16(aA, w2f[s], accA, 0, 0, 0);
            accB = __builtin_amdgcn_mfma_f32_16x16x32_bf16(aB, w2f[s], accB, 0, 0, 0);
        }
        #pragma unroll
        for (int r = 0; r < 2; ++r) {
            float v = fmaxf(fmaxf(accA[2 * r], accA[2 * r + 1]),
                            fmaxf(accB[2 * r], accB[2 * r + 1]));
            v = fmaxf(v + bias2, 0.f);
            int qc = (bq << 1) + r;
            s_feat[mm * 64 + q * 8 + qc] = f2bf(v);   // flat = ci*64 + y*8 + x
        }
    }
    __syncthreads();

    {   // coalesced feature writeout (bf16)
        const uint2* sp = (const uint2*)s_feat;
        uint2 v = sp[tid];
        *(uint2*)&feat[blk * 1024 + tid * 4] = v;
    }
}

// ---------------- K2: fc1 (+relu) fused with fc2 -> heat ---------------------
__global__ __launch_bounds__(256) void k2_fc(
    const u16* __restrict__ feat, const u16* __restrict__ fc1T,
    const float* __restrict__ bfc1, const float* __restrict__ wfc2,
    const float* __restrict__ cst, float* __restrict__ out)
{
    __shared__ u16 sA[64 * 136];
    __shared__ u16 sB[128 * 136];
    const int tid = threadIdx.x;
    const int lane = tid & 63;
    const int wv = tid >> 6;
    const int mm = lane & 15;
    const int bq = lane >> 4;
    const int p0 = blockIdx.x * 64;

    f32x4 acc[8];
    #pragma unroll
    for (int i = 0; i < 8; ++i) acc[i] = (f32x4){0, 0, 0, 0};

    for (int kt = 0; kt < 8; ++kt) {
        for (int i = tid; i < 1024; i += 256) {         // A tile 64x128
            int row = i >> 4, ch = i & 15;
            *(short8*)&sA[row * 136 + ch * 8] =
                *(const short8*)&feat[(p0 + row) * 1024 + kt * 128 + ch * 8];
        }
        for (int i = tid; i < 2048; i += 256) {         // B tile [n][k] 128x128
            int row = i >> 4, ch = i & 15;
            *(short8*)&sB[row * 136 + ch * 8] =
                *(const short8*)&fc1T[row * 1024 + kt * 128 + ch * 8];
        }
        __syncthreads();
        #pragma unroll
        for (int ks = 0; ks < 4; ++ks) {
            short8 aF = *(const short8*)&sA[(wv * 16 + mm) * 136 + ks * 32 + bq * 8];
            #pragma unroll
            for (int nt = 0; nt < 8; ++nt) {
                short8 bF = *(const short8*)&sB[(nt * 16 + mm) * 136 + ks * 32 + bq * 8];
                acc[nt] = __builtin_amdgcn_mfma_f32_16x16x32_bf16(aF, bF, acc[nt], 0, 0, 0);
            }
        }
        __syncthreads();
    }

    const float cpose = *cst;
    float qs[4] = {0, 0, 0, 0};
    #pragma unroll
    for (int nt = 0; nt < 8; ++nt) {
        int n = nt * 16 + mm;
        float bb = bfc1[n], wf = wfc2[n];
        #pragma unroll
        for (int r = 0; r < 4; ++r) {
            float f = fmaxf(acc[nt][r] + bb, 0.f);
            qs[r] += f * wf;
        }
    }
    #pragma unroll
    for (int r = 0; r < 4; ++r) {             // reduce across the 16 n-lanes
        float v = qs[r];
        v += __shfl_xor(v, 1);
        v += __shfl_xor(v, 2);
        v += __shfl_xor(v, 4);
        v += __shfl_xor(v, 8);
        qs[r] = v;
    }
    if (mm == 0) {
        #pragma unroll
        for (int r = 0; r < 4; ++r) {
            int p = p0 + wv * 16 + bq * 4 + r;
            int qy = p / 96, qx = p % 96;
            out[(16 + qy) * 128 + (16 + qx)] = qs[r] + cpose;
        }
    }
}

// ---------------- launch -----------------------------------------------------
extern "C" void kernel_launch(void* const* d_in, const int* in_sizes, int n_in,
                              void* d_out, int out_size, void* d_ws, size_t ws_size,
                              hipStream_t stream)
{
    const float* x     = (const float*)d_in[0];
    const float* z     = (const float*)d_in[1];
    const float* w1    = (const float*)d_in[2];
    const float* b1    = (const float*)d_in[3];
    const float* w2    = (const float*)d_in[4];
    const float* b2    = (const float*)d_in[5];
    const float* wfc1  = (const float*)d_in[6];
    const float* bfc1  = (const float*)d_in[7];
    const float* wpose = (const float*)d_in[8];
    const float* bpose = (const float*)d_in[9];
    const float* wfc2  = (const float*)d_in[10];
    const float* bfc2  = (const float*)d_in[11];
    float* out = (float*)d_out;

    char* ws = (char*)d_ws;
    u16*   w1p  = (u16*)(ws + 0);        // 3072 B
    u16*   w2p  = (u16*)(ws + 4096);     // 13312 B
    float* cst  = (float*)(ws + 20480);  // 4 B
    u16*   fc1T = (u16*)(ws + 24576);    // 262144 B
    u16*   feat = (u16*)(ws + 294912);   // 18874368 B

    hipLaunchKernelGGL(k0_prep, dim3(64), dim3(256), 0, stream,
                       z, w1, w2, wfc1, wpose, bpose, wfc2, bfc2,
                       out, w1p, w2p, fc1T, cst);
    hipLaunchKernelGGL(k1_feat, dim3(9216), dim3(256), 0, stream,
                       x, w1p, w2p, b1, b2, feat);
    hipLaunchKernelGGL(k2_fc, dim3(144), dim3(256), 0, stream,
                       feat, fc1T, bfc1, wfc2, cst, out);
}

// Round 2
// 132.278 us; speedup vs baseline: 1.0812x; 1.0812x over previous
//
#include <hip/hip_runtime.h>

typedef __attribute__((ext_vector_type(8))) short short8;
typedef __attribute__((ext_vector_type(4))) float f32x4;
typedef unsigned short u16;

__device__ __forceinline__ u16 f2bf(float f) {
    unsigned u = __builtin_bit_cast(unsigned, f);
    unsigned r = u + 0x7fffu + ((u >> 16) & 1u);
    return (u16)(r >> 16);
}

// ---------------- K0: prep (zero out, pack weights, pose const) --------------
// conv1 K-order: K=128 as 32 4-blocks t: t<27 -> (dy=t/3, dxs=(t%3)*4),
// element j4 -> dx=dxs+j4 (dx>8 => zero weight). t>=27 -> zero block.
__global__ __launch_bounds__(256) void k0_prep(
    const float* __restrict__ z, const float* __restrict__ w1,
    const float* __restrict__ w2, const float* __restrict__ wfc1,
    const float* __restrict__ wpose, const float* __restrict__ bpose,
    const float* __restrict__ wfc2, const float* __restrict__ bfc2,
    float* __restrict__ out, u16* __restrict__ w1p, u16* __restrict__ w2p,
    u16* __restrict__ fc1T, float* __restrict__ cst)
{
    int gt = blockIdx.x * 256 + threadIdx.x;   // 0..16383
    out[gt] = 0.f;                             // zero heat (borders stay 0)

    if (gt < 2048) {                           // w1 pack: [4 ksteps][64 lanes][8]
        int l = (gt >> 3) & 63, j = gt & 7, s = gt >> 9;
        int k = s * 32 + ((l >> 4) << 3) + j;
        int o = l & 15;
        int t = k >> 2, j4 = k & 3;
        u16 v = 0;
        if (t < 27) {
            int dy = t / 3, dx = (t % 3) * 4 + j4;
            if (dx <= 8) v = f2bf(w1[o * 81 + dy * 9 + dx]);
        }
        w1p[gt] = v;
    }
    if (gt < 6656) {                           // w2 pack: [13][64][8], k = tap*16+ci
        int l = (gt >> 3) & 63, j = gt & 7, s = gt >> 9;
        int k = s * 32 + ((l >> 4) << 3) + j;
        int o = l & 15;
        int tap = k >> 4, ci = k & 15;
        w2p[gt] = (tap < 25) ? f2bf(w2[o * 400 + ci * 25 + tap]) : (u16)0;
    }
    {                                          // fc1 transpose-pack: [128 n][1024 k]
        int base = gt * 8;
        int n = base >> 10, kk = base & 1023;
        short8 v;
        #pragma unroll
        for (int j = 0; j < 8; ++j) v[j] = (short)f2bf(wfc1[(kk + j) * 128 + n]);
        *(short8*)&fc1T[base] = v;
    }
    if (gt == 0) {                             // pose branch + b_fc2 constant
        float zz = z[0];
        float s = bfc2[0];
        for (int j = 0; j < 16; ++j) {
            float p = fmaxf(zz * wpose[j] + bpose[j], 0.f);
            s += p * wfc2[128 + j];
        }
        *cst = s;
    }
}

// ---------------- K1: per-patch conv1+pool1+conv2+pool2 ----------------------
__global__ __launch_bounds__(256) void k1_feat(
    const float* __restrict__ x, const u16* __restrict__ w1p,
    const u16* __restrict__ w2p, const float* __restrict__ b1g,
    const float* __restrict__ b2g, u16* __restrict__ feat)
{
    __shared__ unsigned s2[40 * 44];     // dup-pair patch: s2[r][c]=(px[c],px[c+1])
    __shared__ u16 s_h1p[20 * 20 * 24];  // pool1 out, padded ring, ch stride 24
    __shared__ u16 s_feat[1024];

    const int tid = threadIdx.x;
    const int lane = tid & 63;
    const int wv = tid >> 6;
    const int mm = lane & 15;
    const int bq = lane >> 4;
    const int blk = blockIdx.x;
    const int py = blk / 96, px = blk % 96;

    {   // zero LDS (pads must be 0)
        uint4 z4 = {0, 0, 0, 0};
        uint4* p1 = (uint4*)s2;
        for (int i = tid; i < 440; i += 256) p1[i] = z4;
        uint4* p2 = (uint4*)s_h1p;
        for (int i = tid; i < 1200; i += 256) p2[i] = z4;
    }

    // weight fragments + biases (L2-hot)
    short8 w1f[4], w2f[13];
    #pragma unroll
    for (int s = 0; s < 4; ++s) w1f[s] = *(const short8*)&w1p[(s * 64 + lane) * 8];
    #pragma unroll
    for (int s = 0; s < 13; ++s) w2f[s] = *(const short8*)&w2p[(s * 64 + lane) * 8];
    const float bias1 = b1g[mm], bias2 = b2g[mm];

    // per-lane conv1 4-block offsets (u32 units): t = s*8 + bq*2 + h2
    int oT[8];
    #pragma unroll
    for (int s = 0; s < 4; ++s)
        #pragma unroll
        for (int h2 = 0; h2 < 2; ++h2) {
            int t = s * 8 + bq * 2 + h2;
            oT[s * 2 + h2] = (t < 27) ? (t / 3) * 44 + (t % 3) * 4 : 0;
        }
    // conv2 tap offsets (u16 units, cell stride 24)
    int c2off[13];
    #pragma unroll
    for (int s = 0; s < 13; ++s) {
        int tap = s * 2 + (bq >> 1);
        if (tap > 24) tap = 0;                 // zero-weight pad tap
        int dy = tap / 5, dx = tap % 5;
        c2off[s] = (dy * 20 + dx) * 24 + (bq & 1) * 8;
    }
    __syncthreads();

    // fill s2 interior: 32 rows x 9 quad-groups
    for (int task = tid; task < 288; task += 256) {
        int ir = task / 9, g = task - ir * 9;
        int ic0 = g * 4 - 4;
        const float* xr = x + (py + ir) * 128 + px;
        u16 b[5];
        #pragma unroll
        for (int vi = 0; vi < 5; ++vi) {
            int ic = ic0 + vi;
            float v = (ic >= 0 && ic < 32) ? xr[ic] : 0.f;
            b[vi] = f2bf(v);
        }
        uint4 w;
        w.x = (unsigned)b[0] | ((unsigned)b[1] << 16);
        w.y = (unsigned)b[1] | ((unsigned)b[2] << 16);
        w.z = (unsigned)b[2] | ((unsigned)b[3] << 16);
        w.w = (unsigned)b[3] | ((unsigned)b[4] << 16);
        *(uint4*)&s2[(4 + ir) * 44 + g * 4] = w;
    }
    __syncthreads();

    union Frag { short8 s; unsigned u[4]; };

    // conv1 (M=16 cols of row pair, N=16 ch, K=128) + fused pool1
    for (int pi = 0; pi < 8; ++pi) {
        int q = wv + ((pi >> 1) << 2);         // 0..15 across waves
        int h = pi & 1;
        int xcol = h * 16 + mm;
        int rbA = (2 * q) * 44 + xcol;
        f32x4 accA = {0, 0, 0, 0}, accB = {0, 0, 0, 0};
        #pragma unroll
        for (int s = 0; s < 4; ++s) {
            Frag fA, fB;
            int p0 = rbA + oT[2 * s], p1 = rbA + oT[2 * s + 1];
            fA.u[0] = s2[p0];      fA.u[1] = s2[p0 + 2];
            fA.u[2] = s2[p1];      fA.u[3] = s2[p1 + 2];
            fB.u[0] = s2[p0 + 44]; fB.u[1] = s2[p0 + 46];
            fB.u[2] = s2[p1 + 44]; fB.u[3] = s2[p1 + 46];
            accA = __builtin_amdgcn_mfma_f32_16x16x32_bf16(fA.s, w1f[s], accA, 0, 0, 0);
            accB = __builtin_amdgcn_mfma_f32_16x16x32_bf16(fB.s, w1f[s], accB, 0, 0, 0);
        }
        #pragma unroll
        for (int r = 0; r < 2; ++r) {          // 2x2 maxpool + bias + relu
            float v = fmaxf(fmaxf(accA[2 * r], accA[2 * r + 1]),
                            fmaxf(accB[2 * r], accB[2 * r + 1]));
            v = fmaxf(v + bias1, 0.f);
            int pc = h * 8 + (bq << 1) + r;
            s_h1p[((2 + q) * 20 + (2 + pc)) * 24 + mm] = f2bf(v);
        }
    }
    __syncthreads();

    // conv2 (M=16 cols of row pair, N=16 ch, K=416) + fused pool2
    for (int pi = 0; pi < 2; ++pi) {
        int q = wv + pi * 4;                   // 0..7
        int base = ((2 * q) * 20 + mm) * 24;
        f32x4 accA = {0, 0, 0, 0}, accB = {0, 0, 0, 0};
        #pragma unroll
        for (int s = 0; s < 13; ++s) {
            short8 aA = *(const short8*)&s_h1p[base + c2off[s]];
            short8 aB = *(const short8*)&s_h1p[base + 480 + c2off[s]];
            accA = __builtin_amdgcn_mfma_f32_16x16x32_bf16(aA, w2f[s], accA, 0, 0, 0);
            accB = __builtin_amdgcn_mfma_f32_16x16x32_bf16(aB, w2f[s], accB, 0, 0, 0);
        }
        #pragma unroll
        for (int r = 0; r < 2; ++r) {
            float v = fmaxf(fmaxf(accA[2 * r], accA[2 * r + 1]),
                            fmaxf(accB[2 * r], accB[2 * r + 1]));
            v = fmaxf(v + bias2, 0.f);
            int qc = (bq << 1) + r;
            s_feat[mm * 64 + q * 8 + qc] = f2bf(v);   // flat = ci*64 + y*8 + x
        }
    }
    __syncthreads();

    {   // coalesced feature writeout (bf16)
        const uint2* sp = (const uint2*)s_feat;
        uint2 v = sp[tid];
        *(uint2*)&feat[blk * 1024 + tid * 4] = v;
    }
}

// ---------------- K2: fc1 (+relu) fused with fc2 -> heat ---------------------
__global__ __launch_bounds__(256) void k2_fc(
    const u16* __restrict__ feat, const u16* __restrict__ fc1T,
    const float* __restrict__ bfc1, const float* __restrict__ wfc2,
    const float* __restrict__ cst, float* __restrict__ out)
{
    __shared__ u16 sA[64 * 136];
    __shared__ u16 sB[128 * 136];
    const int tid = threadIdx.x;
    const int lane = tid & 63;
    const int wv = tid >> 6;
    const int mm = lane & 15;
    const int bq = lane >> 4;
    const int p0 = blockIdx.x * 64;

    f32x4 acc[8];
    #pragma unroll
    for (int i = 0; i < 8; ++i) acc[i] = (f32x4){0, 0, 0, 0};

    for (int kt = 0; kt < 8; ++kt) {
        for (int i = tid; i < 1024; i += 256) {         // A tile 64x128
            int row = i >> 4, ch = i & 15;
            *(short8*)&sA[row * 136 + ch * 8] =
                *(const short8*)&feat[(p0 + row) * 1024 + kt * 128 + ch * 8];
        }
        for (int i = tid; i < 2048; i += 256) {         // B tile [n][k] 128x128
            int row = i >> 4, ch = i & 15;
            *(short8*)&sB[row * 136 + ch * 8] =
                *(const short8*)&fc1T[row * 1024 + kt * 128 + ch * 8];
        }
        __syncthreads();
        #pragma unroll
        for (int ks = 0; ks < 4; ++ks) {
            short8 aF = *(const short8*)&sA[(wv * 16 + mm) * 136 + ks * 32 + bq * 8];
            #pragma unroll
            for (int nt = 0; nt < 8; ++nt) {
                short8 bF = *(const short8*)&sB[(nt * 16 + mm) * 136 + ks * 32 + bq * 8];
                acc[nt] = __builtin_amdgcn_mfma_f32_16x16x32_bf16(aF, bF, acc[nt], 0, 0, 0);
            }
        }
        __syncthreads();
    }

    const float cpose = *cst;
    float qs[4] = {0, 0, 0, 0};
    #pragma unroll
    for (int nt = 0; nt < 8; ++nt) {
        int n = nt * 16 + mm;
        float bb = bfc1[n], wf = wfc2[n];
        #pragma unroll
        for (int r = 0; r < 4; ++r) {
            float f = fmaxf(acc[nt][r] + bb, 0.f);
            qs[r] += f * wf;
        }
    }
    #pragma unroll
    for (int r = 0; r < 4; ++r) {             // reduce across the 16 n-lanes
        float v = qs[r];
        v += __shfl_xor(v, 1);
        v += __shfl_xor(v, 2);
        v += __shfl_xor(v, 4);
        v += __shfl_xor(v, 8);
        qs[r] = v;
    }
    if (mm == 0) {
        #pragma unroll
        for (int r = 0; r < 4; ++r) {
            int p = p0 + wv * 16 + bq * 4 + r;
            int qy = p / 96, qx = p % 96;
            out[(16 + qy) * 128 + (16 + qx)] = qs[r] + cpose;
        }
    }
}

// ---------------- launch -----------------------------------------------------
extern "C" void kernel_launch(void* const* d_in, const int* in_sizes, int n_in,
                              void* d_out, int out_size, void* d_ws, size_t ws_size,
                              hipStream_t stream)
{
    const float* x     = (const float*)d_in[0];
    const float* z     = (const float*)d_in[1];
    const float* w1    = (const float*)d_in[2];
    const float* b1    = (const float*)d_in[3];
    const float* w2    = (const float*)d_in[4];
    const float* b2    = (const float*)d_in[5];
    const float* wfc1  = (const float*)d_in[6];
    const float* bfc1  = (const float*)d_in[7];
    const float* wpose = (const float*)d_in[8];
    const float* bpose = (const float*)d_in[9];
    const float* wfc2  = (const float*)d_in[10];
    const float* bfc2  = (const float*)d_in[11];
    float* out = (float*)d_out;

    char* ws = (char*)d_ws;
    u16*   w1p  = (u16*)(ws + 0);        // 4096 B
    u16*   w2p  = (u16*)(ws + 4096);     // 13312 B
    float* cst  = (float*)(ws + 20480);  // 4 B
    u16*   fc1T = (u16*)(ws + 24576);    // 262144 B
    u16*   feat = (u16*)(ws + 294912);   // 18874368 B

    hipLaunchKernelGGL(k0_prep, dim3(64), dim3(256), 0, stream,
                       z, w1, w2, wfc1, wpose, bpose, wfc2, bfc2,
                       out, w1p, w2p, fc1T, cst);
    hipLaunchKernelGGL(k1_feat, dim3(9216), dim3(256), 0, stream,
                       x, w1p, w2p, b1, b2, feat);
    hipLaunchKernelGGL(k2_fc, dim3(144), dim3(256), 0, stream,
                       feat, fc1T, bfc1, wfc2, cst, out);
}

// Round 3
// 115.230 us; speedup vs baseline: 1.2411x; 1.1479x over previous
//
#include <hip/hip_runtime.h>

typedef __attribute__((ext_vector_type(8))) short short8;
typedef __attribute__((ext_vector_type(4))) float f32x4;
typedef unsigned short u16;

__device__ __forceinline__ u16 f2bf(float f) {
    unsigned u = __builtin_bit_cast(unsigned, f);
    unsigned r = u + 0x7fffu + ((u >> 16) & 1u);
    return (u16)(r >> 16);
}

// ---------------- K0: prep (zero out, pack weights, pose const) --------------
// conv1 K-map (5 ksteps): lane bq<3, j: tap dy = (s<4) ? 2s+(j>=4) : 8 (j<4 only),
//   dx = bq*4 + (j&3) (dx>8 -> 0). bq==3 -> all zero.
// conv2 K-map (13 ksteps): s<5: (dy=s, dx=bq>>1, c8=bq&1); s<10: (dy=s-5,
//   dx=2+(bq>>1), c8=bq&1); else: (dy=(s-10)+3*(bq&1), dx=4, c8=bq>>1), dy>4 -> 0.
__global__ __launch_bounds__(256) void k0_prep(
    const float* __restrict__ z, const float* __restrict__ w1,
    const float* __restrict__ w2, const float* __restrict__ wfc1,
    const float* __restrict__ wpose, const float* __restrict__ bpose,
    const float* __restrict__ wfc2, const float* __restrict__ bfc2,
    float* __restrict__ out, u16* __restrict__ w1p, u16* __restrict__ w2p,
    u16* __restrict__ fc1T, float* __restrict__ cst)
{
    int gt = blockIdx.x * 256 + threadIdx.x;   // 0..16383
    out[gt] = 0.f;                             // zero heat (borders stay 0)

    if (gt < 2560) {                           // w1 pack: [5 ksteps][64 lanes][8]
        int l = (gt >> 3) & 63, j = gt & 7, s = gt >> 9;
        int o = l & 15, bq = l >> 4;
        u16 v = 0;
        if (bq < 3) {
            int dx = bq * 4 + (j & 3);
            int dy = -1;
            if (s < 4) dy = 2 * s + (j >> 2);
            else if (j < 4) dy = 8;
            if (dy >= 0 && dx <= 8) v = f2bf(w1[o * 81 + dy * 9 + dx]);
        }
        w1p[gt] = v;
    }
    if (gt < 6656) {                           // w2 pack: [13][64][8]
        int l = (gt >> 3) & 63, j = gt & 7, s = gt >> 9;
        int o = l & 15, bq = l >> 4;
        int dy, dx, c8; bool valid = true;
        if (s < 5)       { dy = s;     dx = bq >> 1;       c8 = bq & 1; }
        else if (s < 10) { dy = s - 5; dx = 2 + (bq >> 1); c8 = bq & 1; }
        else { dy = (s - 10) + 3 * (bq & 1); dx = 4; c8 = bq >> 1; valid = (dy <= 4); }
        int ci = c8 * 8 + j;
        w2p[gt] = valid ? f2bf(w2[o * 400 + ci * 25 + dy * 5 + dx]) : (u16)0;
    }
    {                                          // fc1 transpose-pack: [128 n][1024 k]
        int base = gt * 8;
        int n = base >> 10, kk = base & 1023;
        short8 v;
        #pragma unroll
        for (int j = 0; j < 8; ++j) v[j] = (short)f2bf(wfc1[(kk + j) * 128 + n]);
        *(short8*)&fc1T[base] = v;
    }
    if (gt == 0) {                             // pose branch + b_fc2 constant
        float zz = z[0];
        float s = bfc2[0];
        for (int j = 0; j < 16; ++j) {
            float p = fmaxf(zz * wpose[j] + bpose[j], 0.f);
            s += p * wfc2[128 + j];
        }
        *cst = s;
    }
}

// ---------------- K1: per-patch conv1+pool1+conv2+pool2 ----------------------
__global__ __launch_bounds__(256, 3) void k1_feat(
    const float* __restrict__ x, const u16* __restrict__ w1p,
    const u16* __restrict__ w2p, const float* __restrict__ b1g,
    const float* __restrict__ b2g, u16* __restrict__ feat)
{
    __shared__ unsigned s2[40 * 44];     // dup-pair patch rows -4..35, entry e=(pix e-4, e-3)
    __shared__ u16 s_h1p[20 * 20 * 24];  // pool1, ring-padded, cell stride 24 u16
    __shared__ unsigned s_feat[512];     // swizzled packed features

    const int tid = threadIdx.x;
    const int lane = tid & 63;
    const int wv = tid >> 6;
    const int mm = lane & 15;
    const int bq = lane >> 4;
    const int blk = blockIdx.x;
    const int py = blk / 96, px = blk % 96;

    {   // selective zero: s2 pad rows + right pad cols
        uint4 z4 = {0, 0, 0, 0};
        for (int i = tid; i < 152; i += 256) {
            int dst;
            if (i < 88) { int r8 = i / 11, c4 = i % 11;
                          int row = (r8 < 4) ? r8 : 32 + r8; dst = row * 11 + c4; }
            else        { int j = i - 88; dst = (4 + (j >> 1)) * 11 + 9 + (j & 1); }
            ((uint4*)s2)[dst] = z4;
        }
        // s_h1p ring cells only (y or x in {0,1,18,19}), 12 dwords per cell
        for (int i = tid; i < 1728; i += 256) {
            int yx, d;
            if (i < 960) { int r = i / 240, off = i - r * 240;
                           int y = (r < 2) ? r : 16 + r;
                           yx = y * 20 + off / 12; d = off % 12; }
            else { int j = i - 960; int yy = 2 + j / 48; int rest = j % 48;
                   int xs = rest / 12; d = rest % 12;
                   int xx = (xs < 2) ? xs : 16 + xs; yx = yy * 20 + xx; }
            ((unsigned*)s_h1p)[yx * 12 + d] = 0;
        }
    }

    // weight fragments + biases (L2-hot)
    short8 w1f[5], w2f[13];
    #pragma unroll
    for (int s = 0; s < 5; ++s) w1f[s] = *(const short8*)&w1p[(s * 64 + lane) * 8];
    #pragma unroll
    for (int s = 0; s < 13; ++s) w2f[s] = *(const short8*)&w2p[(s * 64 + lane) * 8];
    const float bias1 = b1g[mm], bias2 = b2g[mm];

    // fill s2 interior: 32 rows x 9 quad-groups
    for (int task = tid; task < 288; task += 256) {
        int ir = task / 9, g = task - ir * 9;
        int ic0 = g * 4 - 4;
        const float* xr = x + (py + ir) * 128 + px;
        u16 b[5];
        #pragma unroll
        for (int vi = 0; vi < 5; ++vi) {
            int ic = ic0 + vi;
            float v = (ic >= 0 && ic < 32) ? xr[ic] : 0.f;
            b[vi] = f2bf(v);
        }
        uint4 w;
        w.x = (unsigned)b[0] | ((unsigned)b[1] << 16);
        w.y = (unsigned)b[1] | ((unsigned)b[2] << 16);
        w.z = (unsigned)b[2] | ((unsigned)b[3] << 16);
        w.w = (unsigned)b[3] | ((unsigned)b[4] << 16);
        *(uint4*)&s2[(4 + ir) * 44 + g * 4] = w;
    }
    __syncthreads();

    union F { short8 s; unsigned u[4]; };
    const int dxq = (bq == 3) ? 0 : bq;

    // conv1: per (q,h): row-chain U[0..9], 10 MFMAs (5 ksteps x {accA,accB})
    for (int qi = 0; qi < 4; ++qi) {
        int q = wv + qi * 4;
        for (int h = 0; h < 2; ++h) {
            int pb = (2 * q) * 44 + h * 16 + mm + dxq * 4;
            unsigned u0[10], u1[10];
            #pragma unroll
            for (int i = 0; i < 10; ++i) {
                u0[i] = s2[pb + i * 44];
                u1[i] = s2[pb + i * 44 + 2];
            }
            f32x4 accA = {0, 0, 0, 0}, accB = {0, 0, 0, 0};
            #pragma unroll
            for (int s = 0; s < 5; ++s) {
                F a, b;
                a.u[0] = u0[2 * s];     a.u[1] = u1[2 * s];
                a.u[2] = u0[2 * s + 1]; a.u[3] = u1[2 * s + 1];
                int bl = (s < 4) ? 2 * s + 1 : 9;
                int bh = (s < 4) ? 2 * s + 2 : 8;
                b.u[0] = u0[bl]; b.u[1] = u1[bl];
                b.u[2] = u0[bh]; b.u[3] = u1[bh];
                accA = __builtin_amdgcn_mfma_f32_16x16x32_bf16(a.s, w1f[s], accA, 0, 0, 0);
                accB = __builtin_amdgcn_mfma_f32_16x16x32_bf16(b.s, w1f[s], accB, 0, 0, 0);
            }
            #pragma unroll
            for (int r = 0; r < 2; ++r) {      // 2x2 maxpool + bias + relu
                float v = fmaxf(fmaxf(accA[2 * r], accA[2 * r + 1]),
                                fmaxf(accB[2 * r], accB[2 * r + 1]));
                v = fmaxf(v + bias1, 0.f);
                int pc = h * 8 + (bq << 1) + r;
                s_h1p[((2 + q) * 20 + (2 + pc)) * 24 + mm] = f2bf(v);
            }
        }
    }
    __syncthreads();

    // conv2: per q: chains A6/B6/C4 (16 unit reads), 26 MFMAs
    for (int pi = 0; pi < 2; ++pi) {
        int q = wv + pi * 4;
        int c8s = (bq & 1) * 8;
        int baseA = ((2 * q) * 20 + mm + (bq >> 1)) * 24 + c8s;
        int baseB = baseA + 2 * 24;
        int c8C = (bq >> 1) * 8;
        int yC0 = 2 * q + 3 * (bq & 1);
        short8 A6[6], B6[6], C4[4];
        #pragma unroll
        for (int i = 0; i < 6; ++i) {
            A6[i] = *(const short8*)&s_h1p[baseA + i * 480];
            B6[i] = *(const short8*)&s_h1p[baseB + i * 480];
        }
        #pragma unroll
        for (int i = 0; i < 4; ++i) {
            int y = yC0 + i; if (y > 19) y = 19;
            C4[i] = *(const short8*)&s_h1p[(y * 20 + mm + 4) * 24 + c8C];
        }
        f32x4 accA = {0, 0, 0, 0}, accB = {0, 0, 0, 0};
        #pragma unroll
        for (int s = 0; s < 5; ++s) {
            accA = __builtin_amdgcn_mfma_f32_16x16x32_bf16(A6[s],     w2f[s], accA, 0, 0, 0);
            accB = __builtin_amdgcn_mfma_f32_16x16x32_bf16(A6[s + 1], w2f[s], accB, 0, 0, 0);
        }
        #pragma unroll
        for (int s = 0; s < 5; ++s) {
            accA = __builtin_amdgcn_mfma_f32_16x16x32_bf16(B6[s],     w2f[5 + s], accA, 0, 0, 0);
            accB = __builtin_amdgcn_mfma_f32_16x16x32_bf16(B6[s + 1], w2f[5 + s], accB, 0, 0, 0);
        }
        #pragma unroll
        for (int s = 0; s < 3; ++s) {
            accA = __builtin_amdgcn_mfma_f32_16x16x32_bf16(C4[s],     w2f[10 + s], accA, 0, 0, 0);
            accB = __builtin_amdgcn_mfma_f32_16x16x32_bf16(C4[s + 1], w2f[10 + s], accB, 0, 0, 0);
        }
        float v0, v1;
        {
            float a = fmaxf(fmaxf(accA[0], accA[1]), fmaxf(accB[0], accB[1]));
            v0 = fmaxf(a + bias2, 0.f);
            float b = fmaxf(fmaxf(accA[2], accA[3]), fmaxf(accB[2], accB[3]));
            v1 = fmaxf(b + bias2, 0.f);
        }
        unsigned dwv = (unsigned)f2bf(v0) | ((unsigned)f2bf(v1) << 16);
        s_feat[mm * 32 + ((q * 4 + bq) ^ mm)] = dwv;   // XOR-swizzled
    }
    __syncthreads();

    {   // coalesced feature writeout (bf16), unswizzle
        int ci = tid >> 4, t = tid & 15;
        uint2 v;
        v.x = s_feat[ci * 32 + ((2 * t) ^ ci)];
        v.y = s_feat[ci * 32 + ((2 * t + 1) ^ ci)];
        *(uint2*)&feat[blk * 1024 + tid * 4] = v;
    }
}

// ---------------- K2: fc1 (+relu) fused with fc2 -> heat ---------------------
__global__ __launch_bounds__(256) void k2_fc(
    const u16* __restrict__ feat, const u16* __restrict__ fc1T,
    const float* __restrict__ bfc1, const float* __restrict__ wfc2,
    const float* __restrict__ cst, float* __restrict__ out)
{
    __shared__ u16 sA[64 * 136];
    __shared__ u16 sB[128 * 136];
    const int tid = threadIdx.x;
    const int lane = tid & 63;
    const int wv = tid >> 6;
    const int mm = lane & 15;
    const int bq = lane >> 4;
    const int p0 = blockIdx.x * 64;

    f32x4 acc[8];
    #pragma unroll
    for (int i = 0; i < 8; ++i) acc[i] = (f32x4){0, 0, 0, 0};

    for (int kt = 0; kt < 8; ++kt) {
        for (int i = tid; i < 1024; i += 256) {         // A tile 64x128
            int row = i >> 4, ch = i & 15;
            *(short8*)&sA[row * 136 + ch * 8] =
                *(const short8*)&feat[(p0 + row) * 1024 + kt * 128 + ch * 8];
        }
        for (int i = tid; i < 2048; i += 256) {         // B tile [n][k] 128x128
            int row = i >> 4, ch = i & 15;
            *(short8*)&sB[row * 136 + ch * 8] =
                *(const short8*)&fc1T[row * 1024 + kt * 128 + ch * 8];
        }
        __syncthreads();
        #pragma unroll
        for (int ks = 0; ks < 4; ++ks) {
            short8 aF = *(const short8*)&sA[(wv * 16 + mm) * 136 + ks * 32 + bq * 8];
            #pragma unroll
            for (int nt = 0; nt < 8; ++nt) {
                short8 bF = *(const short8*)&sB[(nt * 16 + mm) * 136 + ks * 32 + bq * 8];
                acc[nt] = __builtin_amdgcn_mfma_f32_16x16x32_bf16(aF, bF, acc[nt], 0, 0, 0);
            }
        }
        __syncthreads();
    }

    const float cpose = *cst;
    float qs[4] = {0, 0, 0, 0};
    #pragma unroll
    for (int nt = 0; nt < 8; ++nt) {
        int n = nt * 16 + mm;
        float bb = bfc1[n], wf = wfc2[n];
        #pragma unroll
        for (int r = 0; r < 4; ++r) {
            float f = fmaxf(acc[nt][r] + bb, 0.f);
            qs[r] += f * wf;
        }
    }
    #pragma unroll
    for (int r = 0; r < 4; ++r) {             // reduce across the 16 n-lanes
        float v = qs[r];
        v += __shfl_xor(v, 1);
        v += __shfl_xor(v, 2);
        v += __shfl_xor(v, 4);
        v += __shfl_xor(v, 8);
        qs[r] = v;
    }
    if (mm == 0) {
        #pragma unroll
        for (int r = 0; r < 4; ++r) {
            int p = p0 + wv * 16 + bq * 4 + r;
            int qy = p / 96, qx = p % 96;
            out[(16 + qy) * 128 + (16 + qx)] = qs[r] + cpose;
        }
    }
}

// ---------------- launch -----------------------------------------------------
extern "C" void kernel_launch(void* const* d_in, const int* in_sizes, int n_in,
                              void* d_out, int out_size, void* d_ws, size_t ws_size,
                              hipStream_t stream)
{
    const float* x     = (const float*)d_in[0];
    const float* z     = (const float*)d_in[1];
    const float* w1    = (const float*)d_in[2];
    const float* b1    = (const float*)d_in[3];
    const float* w2    = (const float*)d_in[4];
    const float* b2    = (const float*)d_in[5];
    const float* wfc1  = (const float*)d_in[6];
    const float* bfc1  = (const float*)d_in[7];
    const float* wpose = (const float*)d_in[8];
    const float* bpose = (const float*)d_in[9];
    const float* wfc2  = (const float*)d_in[10];
    const float* bfc2  = (const float*)d_in[11];
    float* out = (float*)d_out;

    char* ws = (char*)d_ws;
    u16*   w1p  = (u16*)(ws + 0);        // 5120 B
    u16*   w2p  = (u16*)(ws + 8192);     // 13312 B
    float* cst  = (float*)(ws + 22528);  // 4 B
    u16*   fc1T = (u16*)(ws + 24576);    // 262144 B
    u16*   feat = (u16*)(ws + 294912);   // 18874368 B

    hipLaunchKernelGGL(k0_prep, dim3(64), dim3(256), 0, stream,
                       z, w1, w2, wfc1, wpose, bpose, wfc2, bfc2,
                       out, w1p, w2p, fc1T, cst);
    hipLaunchKernelGGL(k1_feat, dim3(9216), dim3(256), 0, stream,
                       x, w1p, w2p, b1, b2, feat);
    hipLaunchKernelGGL(k2_fc, dim3(144), dim3(256), 0, stream,
                       feat, fc1T, bfc1, wfc2, cst, out);
}